// Round 4
// baseline (1129.152 us; speedup 1.0000x reference)
//
#include <hip/hip_runtime.h>

#define D 128

typedef short v8s __attribute__((ext_vector_type(8)));
typedef float v4f __attribute__((ext_vector_type(4)));

// fp32 -> bf16 hi/lo split: f ~= hi + lo, |err| ~ 2^-17 * |f|
__device__ __forceinline__ void f2hl(float f, unsigned short& h, unsigned short& l) {
    unsigned int u = __float_as_uint(f);
    unsigned int hu = u & 0xffff0000u;
    float lf = f - __uint_as_float(hu);          // exact
    h = (unsigned short)(hu >> 16);
    l = (unsigned short)((__float_as_uint(lf) + 0x8000u) >> 16);  // round
}

// permuted column position for a 4-aligned k chunk (MFMA A-frag contiguous layout)
// k = 4g + (e&3) + 16*(e>>2)  <->  p = 8g + e   (within each 32-wide k block)
__device__ __forceinline__ int permc(int c) {
    return (c & ~31) + ((c & 12) << 1) + ((c & 16) >> 2);
}

// ---------------- preprocessing (unchanged) ----------------

__global__ void k_count(const int* __restrict__ dst, int* __restrict__ deg, int E) {
    int e = blockIdx.x * 256 + threadIdx.x;
    if (e < E) atomicAdd(&deg[dst[e]], 1);
}

__global__ __launch_bounds__(256) void k_blocksum(const int* __restrict__ deg,
                                                  int* __restrict__ bsums, int N) {
    __shared__ int s[256];
    int base = blockIdx.x * 1024 + threadIdx.x * 4;
    int v = 0;
#pragma unroll
    for (int j = 0; j < 4; ++j) { int i = base + j; if (i < N) v += deg[i]; }
    s[threadIdx.x] = v;
    __syncthreads();
    for (int off = 128; off > 0; off >>= 1) {
        if (threadIdx.x < off) s[threadIdx.x] += s[threadIdx.x + off];
        __syncthreads();
    }
    if (threadIdx.x == 0) bsums[blockIdx.x] = s[0];
}

__global__ __launch_bounds__(256) void k_scanbsums(int* __restrict__ bsums, int NB) {
    __shared__ int s[256];
    __shared__ int carry;
    int t = threadIdx.x;
    if (t == 0) carry = 0;
    __syncthreads();
    for (int base = 0; base < NB; base += 256) {
        int i = base + t;
        int v = (i < NB) ? bsums[i] : 0;
        s[t] = v;
        __syncthreads();
        for (int off = 1; off < 256; off <<= 1) {
            int x = (t >= off) ? s[t - off] : 0;
            __syncthreads();
            s[t] += x;
            __syncthreads();
        }
        if (i < NB) bsums[i] = carry + s[t] - v;   // exclusive
        __syncthreads();
        if (t == 0) carry += s[255];
        __syncthreads();
    }
}

__global__ __launch_bounds__(256) void k_scan2(const int* __restrict__ deg,
                                               const int* __restrict__ bsums,
                                               int* __restrict__ rowst,
                                               float* __restrict__ dinv, int N) {
    __shared__ int s[256];
    int t = threadIdx.x;
    int base = blockIdx.x * 1024 + t * 4;
    int v[4];
#pragma unroll
    for (int j = 0; j < 4; ++j) { int i = base + j; v[j] = (i < N) ? deg[i] : 0; }
    int tsum = v[0] + v[1] + v[2] + v[3];
    s[t] = tsum;
    __syncthreads();
    for (int off = 1; off < 256; off <<= 1) {
        int x = (t >= off) ? s[t - off] : 0;
        __syncthreads();
        s[t] += x;
        __syncthreads();
    }
    int run = s[t] - tsum + bsums[blockIdx.x];
#pragma unroll
    for (int j = 0; j < 4; ++j) {
        int i = base + j;
        if (i < N) {
            rowst[i] = run;
            dinv[i] = rsqrtf((float)(v[j] + 1));   // +1 for self-loop
        }
        run += v[j];
    }
}

__global__ void k_fill(const int* __restrict__ src, const int* __restrict__ dst,
                       const int* __restrict__ rowst, int* __restrict__ cursor,
                       const float* __restrict__ dinv, int2* __restrict__ csr, int E) {
    int e = blockIdx.x * 256 + threadIdx.x;
    if (e >= E) return;
    int s = src[e], d = dst[e];
    int p = rowst[d] + atomicAdd(&cursor[d], 1);
    csr[p] = make_int2(s, __float_as_int(dinv[s] * dinv[d]));
}

// ---------------- weight fragment packing ----------------

// Ws[9][128][128] fp32 -> per-lane MFMA B fragments, hi/lo bf16:
// wf[((l*4+ks)*8+nt)*64 + lane][8 words]: words 0-3 = hi frag, 4-7 = lo frag
__global__ __launch_bounds__(64) void k_wconv(const float* __restrict__ Ws,
                                              unsigned int* __restrict__ wf) {
    int b = blockIdx.x;              // l*32 + ks*8 + nt
    int l = b >> 5, ks = (b >> 3) & 3, nt = b & 7;
    int lane = threadIdx.x;
    int g = lane >> 4, c = (lane & 15) + nt * 16;
    const float* W = Ws + (size_t)l * D * D;
    unsigned int hw[4], lw[4];
#pragma unroll
    for (int w = 0; w < 4; ++w) {
        unsigned short hs[2], ls[2];
#pragma unroll
        for (int j = 0; j < 2; ++j) {
            int e = 2 * w + j;
            int k = ks * 32 + 4 * g + (e & 3) + 16 * (e >> 2);
            f2hl(W[k * D + c], hs[j], ls[j]);
        }
        hw[w] = (unsigned int)hs[0] | ((unsigned int)hs[1] << 16);
        lw[w] = (unsigned int)ls[0] | ((unsigned int)ls[1] << 16);
    }
    unsigned int* dstp = wf + ((size_t)((l * 4 + ks) * 8 + nt) * 64 + lane) * 8;
    *(uint4*)dstp = make_uint4(hw[0], hw[1], hw[2], hw[3]);
    *(uint4*)(dstp + 4) = make_uint4(lw[0], lw[1], lw[2], lw[3]);
}

// Wo[128,16] fp32 -> wof[(ks*64 + lane)*8]: hi frag words 0-3, lo words 4-7
__global__ __launch_bounds__(64) void k_woconv(const float* __restrict__ Wo,
                                               unsigned int* __restrict__ wof) {
    int ks = blockIdx.x;
    int lane = threadIdx.x;
    int g = lane >> 4, c = lane & 15;
    unsigned int hw[4], lw[4];
#pragma unroll
    for (int w = 0; w < 4; ++w) {
        unsigned short hs[2], ls[2];
#pragma unroll
        for (int j = 0; j < 2; ++j) {
            int e = 2 * w + j;
            int k = ks * 32 + 4 * g + (e & 3) + 16 * (e >> 2);
            f2hl(Wo[k * 16 + c], hs[j], ls[j]);
        }
        hw[w] = (unsigned int)hs[0] | ((unsigned int)hs[1] << 16);
        lw[w] = (unsigned int)ls[0] | ((unsigned int)ls[1] << 16);
    }
    unsigned int* dstp = wof + ((size_t)(ks * 64 + lane)) * 8;
    *(uint4*)dstp = make_uint4(hw[0], hw[1], hw[2], hw[3]);
    *(uint4*)(dstp + 4) = make_uint4(lw[0], lw[1], lw[2], lw[3]);
}

// ---------------- fused layer: hout = act( (A_norm . hin) @ W + b ) ----------------
// Phase 1 (edge-balanced): block's CSR edge range split into 8 equal chunks, one per
//   32-lane group. Each group walks its chunk with an unroll-4 load pipeline, carrying
//   a register accumulator for the current dst node; flushes via LDS atomicAdd at node
//   transitions. Self-loop terms pre-written non-atomically. All branches group-uniform.
// Phase 2: 4 waves cover ROWS x (NTT*16) outputs via split-bf16 MFMA, bias(+ReLU).

template <int ROWS, int NTT, int RELU, int OSTRIDE>
__global__ __launch_bounds__(256, 8) void k_fused(const float* __restrict__ hin,
                                                  const int2* __restrict__ csr,
                                                  const int* __restrict__ rowst,
                                                  const int* __restrict__ deg,
                                                  const float* __restrict__ dinv,
                                                  const unsigned int* __restrict__ wf,
                                                  const float* __restrict__ bias,
                                                  float* __restrict__ hout, int N) {
    __shared__ float sT[ROWS * 128];
    __shared__ int sB[ROWS + 1];
    const int nb = blockIdx.x * ROWS;
    const int nv = (N - nb < ROWS) ? (N - nb) : ROWS;

    const int gp = threadIdx.x >> 5;
    const int l32 = threadIdx.x & 31;
    const int c = l32 << 2;
    const int p0 = permc(c);

    // ---- node edge boundaries + self-loop init ----
    {
        int t = threadIdx.x;
        if (t < nv) sB[t] = rowst[nb + t];
        if (t == 0) {
            int ln = nb + nv - 1;
            sB[nv] = rowst[ln] + deg[ln];
        }
    }
    for (int s = gp; s < nv; s += 8) {
        int node = nb + s;
        float di = dinv[node];
        float s2 = di * di;
        float4 t0 = *(const float4*)&hin[(size_t)node * D + c];
        float4 a;
        a.x = s2 * t0.x; a.y = s2 * t0.y; a.z = s2 * t0.z; a.w = s2 * t0.w;
        *(float4*)&sT[s * 128 + (p0 ^ ((s & 7) << 2))] = a;
    }
    __syncthreads();

    // ---- balanced edge walk ----
    {
        const int estart = sB[0];
        const int eend = sB[nv];
        const int TE = eend - estart;
        int e0 = estart + ((TE * gp) >> 3);
        int e1 = estart + ((TE * (gp + 1)) >> 3);
        if (e0 < e1) {
            // first idx in [1,nv] with sB[idx] > e0, minus 1
            int lo = 1, hi = nv;
            while (lo < hi) {
                int mid = (lo + hi) >> 1;
                if (sB[mid] <= e0) lo = mid + 1; else hi = mid;
            }
            int cur = lo - 1;
            int nextb = sB[cur + 1];
            float4 acc = make_float4(0.f, 0.f, 0.f, 0.f);

#define FLUSH_ADV()                                                        \
            {                                                              \
                int idx = cur * 128 + (p0 ^ ((cur & 7) << 2));             \
                atomicAdd(&sT[idx + 0], acc.x);                            \
                atomicAdd(&sT[idx + 1], acc.y);                            \
                atomicAdd(&sT[idx + 2], acc.z);                            \
                atomicAdd(&sT[idx + 3], acc.w);                            \
                acc = make_float4(0.f, 0.f, 0.f, 0.f);                     \
                ++cur; nextb = sB[cur + 1];                                \
            }
#define APPLY(ED, R, EI)                                                   \
            while ((EI) >= nextb) FLUSH_ADV();                             \
            {                                                              \
                float w_ = __int_as_float((ED).y);                         \
                acc.x = fmaf(w_, (R).x, acc.x);                            \
                acc.y = fmaf(w_, (R).y, acc.y);                            \
                acc.z = fmaf(w_, (R).z, acc.z);                            \
                acc.w = fmaf(w_, (R).w, acc.w);                            \
            }

            int e = e0;
            for (; e + 4 <= e1; e += 4) {
                int2 ed0 = csr[e + 0];
                int2 ed1 = csr[e + 1];
                int2 ed2 = csr[e + 2];
                int2 ed3 = csr[e + 3];
                float4 r0 = *(const float4*)&hin[(size_t)ed0.x * D + c];
                float4 r1 = *(const float4*)&hin[(size_t)ed1.x * D + c];
                float4 r2 = *(const float4*)&hin[(size_t)ed2.x * D + c];
                float4 r3 = *(const float4*)&hin[(size_t)ed3.x * D + c];
                APPLY(ed0, r0, e + 0);
                APPLY(ed1, r1, e + 1);
                APPLY(ed2, r2, e + 2);
                APPLY(ed3, r3, e + 3);
            }
            for (; e < e1; ++e) {
                int2 ed = csr[e];
                float4 r = *(const float4*)&hin[(size_t)ed.x * D + c];
                APPLY(ed, r, e);
            }
            // final flush
            {
                int idx = cur * 128 + (p0 ^ ((cur & 7) << 2));
                atomicAdd(&sT[idx + 0], acc.x);
                atomicAdd(&sT[idx + 1], acc.y);
                atomicAdd(&sT[idx + 2], acc.z);
                atomicAdd(&sT[idx + 3], acc.w);
            }
#undef APPLY
#undef FLUSH_ADV
        }
    }
    __syncthreads();

    // ---- phase 2: split-bf16 MFMA ----
    constexpr int WR = ROWS / 16;        // row tiles
    constexpr int CG = 4 / WR;           // col groups (waves per row tile)
    constexpr int NTW = NTT / CG;        // col tiles per wave
    const int w = threadIdx.x >> 6;
    const int lane = threadIdx.x & 63;
    const int q = lane & 15, g = lane >> 4;
    const int rtile = w % WR;
    const int cg = w / WR;
    const int rloc = rtile * 16 + q;
    const int sw = (q & 7) << 2;

    v4f acc[NTW];
#pragma unroll
    for (int nt = 0; nt < NTW; ++nt) acc[nt] = (v4f)0.f;

    const float* rp = &sT[rloc * 128];

#pragma unroll
    for (int ks = 0; ks < 4; ++ks) {
        int o = ks * 32 + g * 8;
        float4 fa = *(const float4*)&rp[o ^ sw];
        float4 fb = *(const float4*)&rp[(o + 4) ^ sw];
        v8s ah, al;
        {
            unsigned short h_, l_;
            f2hl(fa.x, h_, l_); ah[0] = (short)h_; al[0] = (short)l_;
            f2hl(fa.y, h_, l_); ah[1] = (short)h_; al[1] = (short)l_;
            f2hl(fa.z, h_, l_); ah[2] = (short)h_; al[2] = (short)l_;
            f2hl(fa.w, h_, l_); ah[3] = (short)h_; al[3] = (short)l_;
            f2hl(fb.x, h_, l_); ah[4] = (short)h_; al[4] = (short)l_;
            f2hl(fb.y, h_, l_); ah[5] = (short)h_; al[5] = (short)l_;
            f2hl(fb.z, h_, l_); ah[6] = (short)h_; al[6] = (short)l_;
            f2hl(fb.w, h_, l_); ah[7] = (short)h_; al[7] = (short)l_;
        }
        const unsigned int* wk = wf + ((size_t)(ks * NTT + cg * NTW) * 64 + lane) * 8;
#pragma unroll
        for (int nt = 0; nt < NTW; ++nt) {
            v8s wh = *(const v8s*)(wk + nt * 512);
            v8s wl = *(const v8s*)(wk + nt * 512 + 4);
            acc[nt] = __builtin_amdgcn_mfma_f32_16x16x32_bf16(ah, wh, acc[nt], 0, 0, 0);
            acc[nt] = __builtin_amdgcn_mfma_f32_16x16x32_bf16(al, wh, acc[nt], 0, 0, 0);
            acc[nt] = __builtin_amdgcn_mfma_f32_16x16x32_bf16(ah, wl, acc[nt], 0, 0, 0);
        }
    }

    // ---- epilogue: bias (+ReLU), store. C/D layout: col = q, row = 4g + i ----
    const int growb = nb + rtile * 16 + 4 * g;
#pragma unroll
    for (int nt = 0; nt < NTW; ++nt) {
        int col = (cg * NTW + nt) * 16 + q;
        float bv = bias[col];
#pragma unroll
        for (int i = 0; i < 4; ++i) {
            int grow = growb + i;
            if (grow < N) {
                float v = acc[nt][i] + bv;
                if (RELU) v = fmaxf(v, 0.f);
                hout[(size_t)grow * OSTRIDE + col] = v;
            }
        }
    }
}

// ---------------- launch ----------------

extern "C" void kernel_launch(void* const* d_in, const int* in_sizes, int n_in,
                              void* d_out, int out_size, void* d_ws, size_t ws_size,
                              hipStream_t stream) {
    const float* x  = (const float*)d_in[0];
    const int*   ei = (const int*)d_in[1];
    const float* Ws = (const float*)d_in[2];
    const float* bs = (const float*)d_in[3];
    const float* Wo = (const float*)d_in[4];
    const float* bo = (const float*)d_in[5];
    float* out = (float*)d_out;

    const int N = in_sizes[0] / D;     // 100000
    const int E = in_sizes[1] / 2;     // 600000
    const int* src = ei;
    const int* dst = ei + E;

    // workspace layout (~109.4 MB)
    float* H0     = (float*)d_ws;                     // N*128 fp32 ping
    float* H1     = H0 + (size_t)N * D;               // N*128 fp32 pong
    int*   deg    = (int*)(H1 + (size_t)N * D);
    int*   cursor = deg + N;
    int*   rowst  = cursor + N;
    float* dinv   = (float*)(rowst + N);
    int*   bsums  = (int*)(dinv + N);
    int2*  csr    = (int2*)(bsums + 1024);
    unsigned int* wfrag  = (unsigned int*)(csr + E);  // 9 * 16384 uints (576 KB)
    unsigned int* wofrag = wfrag + 9 * 16384;         // 2048 uints (8 KB)

    const int NB = (N + 1023) / 1024;

    hipMemsetAsync(deg, 0, (size_t)2 * N * sizeof(int), stream);  // deg + cursor
    k_count<<<(E + 255) / 256, 256, 0, stream>>>(dst, deg, E);
    k_blocksum<<<NB, 256, 0, stream>>>(deg, bsums, N);
    k_scanbsums<<<1, 256, 0, stream>>>(bsums, NB);
    k_scan2<<<NB, 256, 0, stream>>>(deg, bsums, rowst, dinv, N);
    k_fill<<<(E + 255) / 256, 256, 0, stream>>>(src, dst, rowst, cursor, dinv, csr, E);

    k_wconv<<<288, 64, 0, stream>>>(Ws, wfrag);
    k_woconv<<<4, 64, 0, stream>>>(Wo, wofrag);

    const float* hin = x;
    float* hout = H0;
    const int gblk32 = (N + 31) / 32;
    for (int l = 0; l < 9; ++l) {
        k_fused<32, 8, 1, 128><<<gblk32, 256, 0, stream>>>(hin, csr, rowst, deg, dinv,
                                                           wfrag + (size_t)l * 16384,
                                                           bs + (size_t)l * D, hout, N);
        hin = hout;
        hout = (hout == H0) ? H1 : H0;
    }
    const int gblk64 = (N + 63) / 64;
    k_fused<64, 1, 0, 16><<<gblk64, 256, 0, stream>>>(hin, csr, rowst, deg, dinv,
                                                      wofrag, bo, out, N);
}